// Round 15
// baseline (286.082 us; speedup 1.0000x reference)
//
#include <hip/hip_runtime.h>
#include <hip/hip_bf16.h>

// ---------------------------------------------------------------------------
// GAT (2 layers) — round 15: pipeline repacking.
//   * gemm1 split in half across the two front dispatches:
//       D1 = scatter(831, chunk 2048) + gemm1-A(391), interleaved %3
//       D2 = csr_finalize(512)        + gemm1-B(391), interleaved &1
//     Each pairs latency-bound work with VALU-bound GEMM at 6 blocks/CU.
//   * agg1 / gemm2 / agg2 unchanged (R14; agg kernels at structural
//     L2/L3 random-line-service limits).
// ---------------------------------------------------------------------------

#define SLAB  4096
#define NBUCK 512

typedef float v2f __attribute__((ext_vector_type(2)));

__device__ __forceinline__ float lrelu02(float x) { return x > 0.f ? x : 0.2f * x; }

__device__ __forceinline__ unsigned short f2bf(float v) {
    __hip_bfloat16 b = __float2bfloat16(v);
    return __builtin_bit_cast(unsigned short, b);
}

__device__ __forceinline__ void accum8(uint4 hv, float ex, v2f* acc) {
    v2f ex2 = {ex, ex};
#pragma unroll
    for (int q = 0; q < 4; ++q) {
        unsigned u = (&hv.x)[q];
        v2f h2 = {__uint_as_float(u << 16), __uint_as_float(u & 0xffff0000u)};
        acc[q] = __builtin_elementwise_fma(h2, ex2, acc[q]);
    }
}

__device__ __forceinline__ v2f shfl_xor_v2(v2f v, int mask) {
    v2f r;
    r.x = __shfl_xor(v.x, mask, 64);
    r.y = __shfl_xor(v.y, mask, 64);
    return r;
}

// ----------------------- scatter body (512-bucket slab sort) ----------------
// chunk = 2048 edges/block. LDS: 4*512 ints (8 KB) + ssrc/sdst[2048]
// (16 KB) = 24576 B. Bucket recomputed at flush (no bb[]).
__device__ __forceinline__ void scatter_body(char* smem, int vbid,
                                             const int* __restrict__ ei,
                                             int e_real, int e_total, unsigned M,
                                             int* __restrict__ bcur_pad,
                                             int2* __restrict__ pairs) {
    int* cnt   = (int*)smem;                     // 512
    int* loff  = cnt + 512;                      // 512
    int* lcur  = loff + 512;                     // 512
    int* gbase = lcur + 512;                     // 512
    int* ssrc  = gbase + 512;                    // 2048
    int* sdst  = ssrc + 2048;                    // 2048

    const int t = threadIdx.x;
    const int base = vbid * 2048;
    cnt[t] = 0; cnt[t + 256] = 0;
    __syncthreads();

    int rs[8], rd[8], rb[8];
#pragma unroll
    for (int k = 0; k < 8; ++k) {
        int i = base + k * 256 + t;
        bool val = i < e_total;
        int s = 0, d = 0;
        if (val) {
            if (i < e_real) { s = ei[i]; d = ei[e_real + i]; }
            else            { s = d = i - e_real; }
        }
        int b = val ? (int)__umulhi((unsigned)d, M) : -1;
        rs[k] = s; rd[k] = d; rb[k] = b;
        if (val) atomicAdd(&cnt[b], 1);
    }
    __syncthreads();

    loff[t] = cnt[t]; loff[t + 256] = cnt[t + 256];
    __syncthreads();
    for (int off = 1; off < 512; off <<= 1) {
        int v0 = (t >= off) ? loff[t - off] : 0;
        int v1 = (t + 256 >= off) ? loff[t + 256 - off] : 0;
        __syncthreads();
        loff[t] += v0; loff[t + 256] += v1;
        __syncthreads();
    }
    int e0 = loff[t] - cnt[t];
    int e1 = loff[t + 256] - cnt[t + 256];
    loff[t] = e0;           loff[t + 256] = e1;
    lcur[t] = e0;           lcur[t + 256] = e1;
    gbase[t]       = t * SLAB         + atomicAdd(&bcur_pad[t * 16], cnt[t]);
    gbase[t + 256] = (t + 256) * SLAB + atomicAdd(&bcur_pad[(t + 256) * 16],
                                                  cnt[t + 256]);
    __syncthreads();

#pragma unroll
    for (int k = 0; k < 8; ++k) {
        if (rb[k] >= 0) {
            int lp = atomicAdd(&lcur[rb[k]], 1);
            ssrc[lp] = rs[k];
            sdst[lp] = rd[k];
        }
    }
    __syncthreads();

    int cn = e_total - base; if (cn > 2048) cn = 2048;
    for (int idx = t; idx < cn; idx += 256) {
        int d = sdst[idx];
        int b = (int)__umulhi((unsigned)d, M);           // recompute bucket
        int g = gbase[b] + (idx - loff[b]);
        pairs[g] = make_int2(ssrc[idx], d);              // coalesced runs
    }
}

// ----------------------- CSR finalize body (one bucket) ---------------------
// LDS: bs[512] + deg/sc/cur[256] + ebeg = 5128 B.
__device__ __forceinline__ void finalize_body(char* smem, int b,
                                              const int2* __restrict__ pairs,
                                              const int* __restrict__ bcur_pad,
                                              unsigned M, int n,
                                              int* __restrict__ offsets,
                                              int* __restrict__ srcs) {
    int* bs  = (int*)smem;                 // 512
    int* deg = bs + 512;                   // 256
    int* sc  = deg + 256;                  // 256
    int* cur = sc + 256;                   // 256
    int* ebp = cur + 256;                  // 1

    const int t = threadIdx.x;
    const unsigned long long Mll = M;
    int lo = (int)((((unsigned long long)b << 32) + Mll - 1) / Mll);
    int hi = (int)((((unsigned long long)(b + 1) << 32) + Mll - 1) / Mll);
    if (lo > n) lo = n;
    if (hi > n) hi = n;
    const int R    = hi - lo;                 // <= ~196 < 256
    const int cntb = bcur_pad[b * 16];
    const int2* sp = pairs + (size_t)b * SLAB;

    bs[t] = bcur_pad[t * 16];
    bs[t + 256] = bcur_pad[(t + 256) * 16];
    __syncthreads();
    for (int off = 1; off < NBUCK; off <<= 1) {
        int v0 = (t >= off) ? bs[t - off] : 0;
        int v1 = (t + 256 >= off) ? bs[t + 256 - off] : 0;
        __syncthreads();
        bs[t] += v0; bs[t + 256] += v1;
        __syncthreads();
    }
    if (t == 0) *ebp = (b == 0) ? 0 : bs[b - 1];
    if (b == NBUCK - 1 && t == 0) offsets[n] = bs[NBUCK - 1];
    __syncthreads();
    const int ebeg = *ebp;

    deg[t] = 0;
    __syncthreads();
    for (int j = t; j < cntb; j += 256)
        atomicAdd(&deg[sp[j].y - lo], 1);
    __syncthreads();

    sc[t] = deg[t];
    __syncthreads();
    for (int off = 1; off < 256; off <<= 1) {
        int v = (t >= off) ? sc[t - off] : 0;
        __syncthreads();
        sc[t] += v;
        __syncthreads();
    }
    int e0 = sc[t] - deg[t];
    cur[t] = e0;
    if (t < R) offsets[lo + t] = ebeg + e0;
    __syncthreads();

    for (int j = t; j < cntb; j += 256) {
        int2 p = sp[j];
        int pos = atomicAdd(&cur[p.y - lo], 1);         // LDS atomic
        srcs[ebeg + pos] = p.x;
    }
}

// ------------------------- GEMM + attention logits body ---------------------
template<int K, int OUTC, int H, int C, int NPT, int KCHUNK>
__device__ __forceinline__ void gemm_al_body(char* smem, int vbid,
                                             const float* __restrict__ x,
                                             const float* __restrict__ W,
                                             const float* __restrict__ a_src,
                                             const float* __restrict__ a_dst,
                                             unsigned short* __restrict__ h,
                                             float* __restrict__ al_s,
                                             float* __restrict__ al_d,
                                             int n) {
    constexpr int COLG = OUTC / 4;
    constexpr int NG   = 256 / COLG;
    static_assert(NG * 8 == NPT, "tile mismatch");
    constexpr int LDX  = KCHUNK + 1;
    float* Xs = (float*)smem;                 // NPT*LDX
    float* Ws = Xs + NPT * LDX;               // KCHUNK*OUTC

    const int t    = threadIdx.x;
    const int mg   = t / COLG;
    const int cg   = t % COLG;
    const int base = vbid * NPT;

    float acc[8][4];
#pragma unroll
    for (int i = 0; i < 8; ++i)
#pragma unroll
        for (int j = 0; j < 4; ++j) acc[i][j] = 0.f;

    for (int kc = 0; kc < K; kc += KCHUNK) {
        __syncthreads();
        constexpr int F4R = KCHUNK / 4;
        constexpr int TOTF4 = NPT * F4R;
#pragma unroll
        for (int r = 0; r < TOTF4 / 256; ++r) {
            int f4   = r * 256 + t;
            int node = f4 / F4R;
            int kq   = f4 % F4R;
            int gn   = base + node; if (gn > n - 1) gn = n - 1;
            const float4 v = *(const float4*)&x[(size_t)gn * K + kc + kq * 4];
            float* d = &Xs[node * LDX + kq * 4];
            d[0] = v.x; d[1] = v.y; d[2] = v.z; d[3] = v.w;
        }
        constexpr int WF4 = KCHUNK * OUTC / 4;
        for (int idx = t; idx < WF4; idx += 256)
            *(float4*)&Ws[idx * 4] = *(const float4*)&W[(size_t)kc * OUTC + idx * 4];
        __syncthreads();

#pragma unroll 4
        for (int k = 0; k < KCHUNK; ++k) {
            float4 b = *(const float4*)&Ws[k * OUTC + cg * 4];
            float a[8];
#pragma unroll
            for (int i = 0; i < 8; ++i) a[i] = Xs[(mg * 8 + i) * LDX + k];
#pragma unroll
            for (int i = 0; i < 8; ++i) {
                acc[i][0] += a[i] * b.x;
                acc[i][1] += a[i] * b.y;
                acc[i][2] += a[i] * b.z;
                acc[i][3] += a[i] * b.w;
            }
        }
    }

    const float4 as4 = *(const float4*)&a_src[cg * 4];
    const float4 ad4 = *(const float4*)&a_dst[cg * 4];
    constexpr int GPH = C / 4;
    const int head = cg / GPH;
#pragma unroll
    for (int i = 0; i < 8; ++i) {
        int gn = base + mg * 8 + i;
        bool ok = gn < n;
        if (ok) {
            ushort4 hv;
            hv.x = f2bf(acc[i][0]); hv.y = f2bf(acc[i][1]);
            hv.z = f2bf(acc[i][2]); hv.w = f2bf(acc[i][3]);
            *(ushort4*)&h[(size_t)gn * OUTC + cg * 4] = hv;
        }
        float ps = acc[i][0] * as4.x + acc[i][1] * as4.y +
                   acc[i][2] * as4.z + acc[i][3] * as4.w;
        float pd = acc[i][0] * ad4.x + acc[i][1] * ad4.y +
                   acc[i][2] * ad4.z + acc[i][3] * ad4.w;
#pragma unroll
        for (int s = 1; s < GPH; s <<= 1) {
            ps += __shfl_xor(ps, s, 64);
            pd += __shfl_xor(pd, s, 64);
        }
        if (ok && (cg % GPH) == 0) {
            al_s[(size_t)gn * H + head] = ps;
            al_d[(size_t)gn * H + head] = pd;
        }
    }
}

// --------- D1: scatter (831) + gemm1 first half (391), interleaved %3 -------
__global__ __launch_bounds__(256)
void d1_kernel(const int* __restrict__ ei, int e_real, int e_total,
               unsigned M, int* __restrict__ bcur_pad,
               int2* __restrict__ pairs, int ns, int ga,
               const float* __restrict__ x,
               const float* __restrict__ W1,
               const float* __restrict__ as1,
               const float* __restrict__ ad1,
               unsigned short* __restrict__ h,
               float* __restrict__ al_s,
               float* __restrict__ al_d, int n) {
    __shared__ __align__(16) char smem[25088];  // max(scatter 24576, gemm 25088)
    const int g = blockIdx.x / 3;
    const int r = blockIdx.x - g * 3;
    if (r < 2) {
        int sv = g * 2 + r;
        if (sv < ns)
            scatter_body(smem, sv, ei, e_real, e_total, M, bcur_pad, pairs);
    } else {
        if (g < ga)
            gemm_al_body<128, 64, 8, 8, 128, 32>(smem, g, x, W1, as1, ad1,
                                                 h, al_s, al_d, n);
    }
}

// --------- D2: csr_finalize (512) + gemm1 second half (391), interleaved &1 -
__global__ __launch_bounds__(256)
void d2_kernel(const int2* __restrict__ pairs,
               const int* __restrict__ bcur_pad, unsigned M,
               int* __restrict__ offsets, int* __restrict__ srcs,
               int ga, int g1,
               const float* __restrict__ x,
               const float* __restrict__ W1,
               const float* __restrict__ as1,
               const float* __restrict__ ad1,
               unsigned short* __restrict__ h,
               float* __restrict__ al_s,
               float* __restrict__ al_d, int n) {
    __shared__ __align__(16) char smem[25088];  // max(finalize 5128, gemm 25088)
    const int bid = blockIdx.x;
    if (bid < 782) {
        const int g = bid >> 1;
        if (bid & 1) {
            int gv = ga + g;                    // 391..781
            if (gv < g1)
                gemm_al_body<128, 64, 8, 8, 128, 32>(smem, gv, x, W1, as1, ad1,
                                                     h, al_s, al_d, n);
        } else {
            finalize_body(smem, g, pairs, bcur_pad, M, n, offsets, srcs);
        }
    } else {
        finalize_body(smem, 391 + (bid - 782), pairs, bcur_pad, M, n,
                      offsets, srcs);
    }
}

// standalone GEMM kernel (layer 2)
template<int K, int OUTC, int H, int C, int NPT, int KCHUNK>
__global__ __launch_bounds__(256)
void gemm_al_kernel(const float* __restrict__ x, const float* __restrict__ W,
                    const float* __restrict__ a_src, const float* __restrict__ a_dst,
                    unsigned short* __restrict__ h, float* __restrict__ al_s,
                    float* __restrict__ al_d, int n) {
    __shared__ __align__(16) char smem[(NPT * (KCHUNK + 1) + KCHUNK * OUTC) * 4];
    gemm_al_body<K, OUTC, H, C, NPT, KCHUNK>(smem, blockIdx.x, x, W, a_src,
                                             a_dst, h, al_s, al_d, n);
}

// ------------------------- fused gather aggregation -------------------------
template<int H, int C>
__global__ __launch_bounds__(256)
void gat_agg_kernel(const int* __restrict__ offsets,
                    const int* __restrict__ srcs,
                    const float* __restrict__ al_s,
                    const float* __restrict__ al_d,
                    const unsigned short* __restrict__ hfeat, // bf16
                    const float* __restrict__ bias,
                    float* __restrict__ out, int n) {
    constexpr int OUTC = H * C;
    constexpr int CG   = OUTC / 8;           // channel groups (8 or 4)
    constexpr int ES   = 64 / CG;            // edge slots (8 or 16)
    const int wid  = (int)((blockIdx.x * blockDim.x + threadIdx.x) >> 6);
    const int lane = threadIdx.x & 63;
    const int cg   = lane % CG;
    const int es   = lane / CG;
    if (wid >= n) return;
    const int head = (cg * 8) / C;

    const float aldv = al_d[(size_t)wid * H + head];
    const int beg = offsets[wid];
    const int end = offsets[wid + 1];
    const int deg = end - beg;

    v2f acc[4];
#pragma unroll
    for (int q = 0; q < 4; ++q) acc[q] = (v2f){0.f, 0.f};
    float dsum = 0.f;

    if (deg <= ES) {
        int j = beg + es;
        bool v = j < end;
        int s = __builtin_nontemporal_load(&srcs[v ? j : beg]);
        const uint4 hv = *(const uint4*)&hfeat[(size_t)s * OUTC + cg * 8];
        float ls = al_s[(size_t)s * H + head];
        float ex = v ? __expf(lrelu02(ls + aldv)) : 0.f;
        accum8(hv, ex, acc);
        dsum += ex;
    } else if (deg <= 2 * ES) {
        int sA = __builtin_nontemporal_load(&srcs[beg + es]);
        int jB = beg + ES + es;
        bool vB = jB < end;
        int sB = __builtin_nontemporal_load(&srcs[vB ? jB : beg]);
        const uint4 hvA = *(const uint4*)&hfeat[(size_t)sA * OUTC + cg * 8];
        const uint4 hvB = *(const uint4*)&hfeat[(size_t)sB * OUTC + cg * 8];
        float lsA = al_s[(size_t)sA * H + head];
        float lsB = al_s[(size_t)sB * H + head];
        float exA = __expf(lrelu02(lsA + aldv));
        float exB = vB ? __expf(lrelu02(lsB + aldv)) : 0.f;
        accum8(hvA, exA, acc);
        accum8(hvB, exB, acc);
        dsum += exA + exB;
    } else if (deg <= 4 * ES) {
        int sA = __builtin_nontemporal_load(&srcs[beg + es]);
        int sB = __builtin_nontemporal_load(&srcs[beg + ES + es]);
        int jC = beg + 2 * ES + es;
        int jD = beg + 3 * ES + es;
        bool vC = jC < end;
        bool vD = jD < end;
        int sC = __builtin_nontemporal_load(&srcs[vC ? jC : beg]);
        int sD = __builtin_nontemporal_load(&srcs[vD ? jD : beg]);
        const uint4 hvA = *(const uint4*)&hfeat[(size_t)sA * OUTC + cg * 8];
        const uint4 hvB = *(const uint4*)&hfeat[(size_t)sB * OUTC + cg * 8];
        const uint4 hvC = *(const uint4*)&hfeat[(size_t)sC * OUTC + cg * 8];
        const uint4 hvD = *(const uint4*)&hfeat[(size_t)sD * OUTC + cg * 8];
        float lsA = al_s[(size_t)sA * H + head];
        float lsB = al_s[(size_t)sB * H + head];
        float lsC = al_s[(size_t)sC * H + head];
        float lsD = al_s[(size_t)sD * H + head];
        float exA = __expf(lrelu02(lsA + aldv));
        float exB = __expf(lrelu02(lsB + aldv));
        float exC = vC ? __expf(lrelu02(lsC + aldv)) : 0.f;
        float exD = vD ? __expf(lrelu02(lsD + aldv)) : 0.f;
        accum8(hvA, exA, acc);
        accum8(hvB, exB, acc);
        accum8(hvC, exC, acc);
        accum8(hvD, exD, acc);
        dsum += (exA + exB) + (exC + exD);
    } else {
        for (int j0 = beg; j0 < end; j0 += 2 * ES) {
            int jA = j0 + es;
            int jB = j0 + ES + es;
            bool vA = jA < end;
            bool vB = jB < end;
            int sA = __builtin_nontemporal_load(&srcs[vA ? jA : beg]);
            int sB = __builtin_nontemporal_load(&srcs[vB ? jB : beg]);
            const uint4 hvA = *(const uint4*)&hfeat[(size_t)sA * OUTC + cg * 8];
            const uint4 hvB = *(const uint4*)&hfeat[(size_t)sB * OUTC + cg * 8];
            float lsA = al_s[(size_t)sA * H + head];
            float lsB = al_s[(size_t)sB * H + head];
            float exA = vA ? __expf(lrelu02(lsA + aldv)) : 0.f;
            float exB = vB ? __expf(lrelu02(lsB + aldv)) : 0.f;
            accum8(hvA, exA, acc);
            accum8(hvB, exB, acc);
            dsum += exA + exB;
        }
    }

#pragma unroll
    for (int sh = CG; sh < 64; sh <<= 1) {
        dsum += __shfl_xor(dsum, sh, 64);
#pragma unroll
        for (int q = 0; q < 4; ++q) acc[q] += shfl_xor_v2(acc[q], sh);
    }

    if (es == 0) {
        float inv = 1.f / dsum;
        const float4 b0 = *(const float4*)&bias[cg * 8];
        const float4 b1v = *(const float4*)&bias[cg * 8 + 4];
        float4 o0, o1;
        o0.x = acc[0].x * inv + b0.x;
        o0.y = acc[0].y * inv + b0.y;
        o0.z = acc[1].x * inv + b0.z;
        o0.w = acc[1].y * inv + b0.w;
        o1.x = acc[2].x * inv + b1v.x;
        o1.y = acc[2].y * inv + b1v.y;
        o1.z = acc[3].x * inv + b1v.z;
        o1.w = acc[3].y * inv + b1v.w;
        *(float4*)&out[(size_t)wid * OUTC + cg * 8]     = o0;
        *(float4*)&out[(size_t)wid * OUTC + cg * 8 + 4] = o1;
    }
}

// ---------------------------------------------------------------------------

extern "C" void kernel_launch(void* const* d_in, const int* in_sizes, int n_in,
                              void* d_out, int out_size, void* d_ws, size_t ws_size,
                              hipStream_t stream) {
    const float* x   = (const float*)d_in[0];
    const int*   ei  = (const int*)  d_in[1];
    const float* W1  = (const float*)d_in[2];
    const float* as1 = (const float*)d_in[3];
    const float* ad1 = (const float*)d_in[4];
    const float* b1  = (const float*)d_in[5];
    const float* W2  = (const float*)d_in[6];
    const float* as2 = (const float*)d_in[7];
    const float* ad2 = (const float*)d_in[8];
    const float* b2  = (const float*)d_in[9];
    float* out = (float*)d_out;

    const int n       = in_sizes[0] / 128;   // 100000
    const int e_real  = in_sizes[1] / 2;     // 1600000
    const int e_total = e_real + n;
    const unsigned M512 = (unsigned)(((unsigned long long)NBUCK << 32) / (unsigned)n);

    // ------------- workspace layout -------------
    unsigned short* h1u = (unsigned short*)d_ws;       // n*64 bf16 (l2: n*32)
    float* fws  = (float*)d_ws;
    float* als1 = fws  + (size_t)n * 32;               // n*8  (l2: n)
    float* ald1 = als1 + (size_t)n * 8;                // n*8  (l2: n)
    float* agg1 = ald1 + (size_t)n * 8;                // n*64 fp32 (layer1 out)
    int2*  pairs = (int2*)agg1;                        // ALIAS: NBUCK*SLAB int2
    int* offsets  = (int*)(agg1 + (size_t)n * 64);     // n+1
    int* srcs     = offsets + (n + 1);                 // e_total
    int* bcur_pad = srcs + e_total;                    // NBUCK*16

    const int ns = (e_total + 2047) / 2048;            // scatter blocks (831)
    const int g1 = (n + 127) / 128;                    // gemm1 blocks (782)
    const int ga = (g1 + 1) / 2;                       // first half (391)

    // ------------- D1: scatter + gemm1-A -------------
    hipMemsetAsync(bcur_pad, 0, NBUCK * 16 * sizeof(int), stream);
    {
        const int groups = (ns + 1) / 2;               // 416
        d1_kernel<<<groups * 3, 256, 0, stream>>>(
            ei, e_real, e_total, M512, bcur_pad, pairs, ns, ga,
            x, W1, as1, ad1, h1u, als1, ald1, n);
    }

    // ------------- D2: csr_finalize + gemm1-B -------------
    d2_kernel<<<782 + (NBUCK - 391), 256, 0, stream>>>(
        pairs, bcur_pad, M512, offsets, srcs, ga, g1,
        x, W1, as1, ad1, h1u, als1, ald1, n);

    // ------------- layer 1 aggregation -------------
    gat_agg_kernel<8, 8><<<(n + 3) / 4, 256, 0, stream>>>(
        offsets, srcs, als1, ald1, h1u, b1, agg1, n);

    // ------------- layer 2: K=64, H=1, C=32 -------------
    gemm_al_kernel<64, 32, 1, 32, 256, 32><<<(n + 255) / 256, 256, 0, stream>>>(
        agg1, W2, as2, ad2, h1u, als1, ald1, n);
    gat_agg_kernel<1, 32><<<(n + 3) / 4, 256, 0, stream>>>(
        offsets, srcs, als1, ald1, h1u, b2, out, n);
}

// Round 16
// 267.223 us; speedup vs baseline: 1.0706x; 1.0706x over previous
//
#include <hip/hip_runtime.h>
#include <hip/hip_bf16.h>

// ---------------------------------------------------------------------------
// GAT (2 layers) — round 16 = R14 revert (best: 269.6 us).
// Final structure:
//   D1  scatter_gemm : 512-bucket slab sort (LDS-staged, no global-atomic
//        write amplification) merged with layer-1 GEMM blocks.
//   D2  csr_finalize : per-bucket LDS deg/scan/cursor -> offsets + srcs.
//   D3  gat_agg<8,8> : degree-specialized edge-slot gather (structural
//        L2/L3 random-line-service floor; FETCH ~149 MB = 8-XCD dup).
//   D4  gemm_al (layer 2)
//   D5  gat_agg<1,32>
// Rejected by experiment: agg+gemm2 fusion (R12 +42us barrier tax, R13
// +86us register tax), pipeline repack (R15 +16us), nt-loads on scatter
// (R6), packed-math gains (R10 neutral — agg is line-service-bound).
// ---------------------------------------------------------------------------

#define SLAB  4096
#define NBUCK 512

typedef float v2f __attribute__((ext_vector_type(2)));

__device__ __forceinline__ float lrelu02(float x) { return x > 0.f ? x : 0.2f * x; }

__device__ __forceinline__ unsigned short f2bf(float v) {
    __hip_bfloat16 b = __float2bfloat16(v);
    return __builtin_bit_cast(unsigned short, b);
}

__device__ __forceinline__ void accum8(uint4 hv, float ex, v2f* acc) {
    v2f ex2 = {ex, ex};
#pragma unroll
    for (int q = 0; q < 4; ++q) {
        unsigned u = (&hv.x)[q];
        v2f h2 = {__uint_as_float(u << 16), __uint_as_float(u & 0xffff0000u)};
        acc[q] = __builtin_elementwise_fma(h2, ex2, acc[q]);
    }
}

__device__ __forceinline__ v2f shfl_xor_v2(v2f v, int mask) {
    v2f r;
    r.x = __shfl_xor(v.x, mask, 64);
    r.y = __shfl_xor(v.y, mask, 64);
    return r;
}

// ----------------------- scatter body (512-bucket slab sort) ----------------
__device__ __forceinline__ void scatter_body(char* smem, int vbid,
                                             const int* __restrict__ ei,
                                             int e_real, int e_total, unsigned M,
                                             int* __restrict__ bcur_pad,
                                             int2* __restrict__ pairs) {
    int* cnt   = (int*)smem;                     // 512
    int* loff  = cnt + 512;                      // 512
    int* lcur  = loff + 512;                     // 512
    int* gbase = lcur + 512;                     // 512
    int* ssrc  = gbase + 512;                    // 4096
    int* sdst  = ssrc + 4096;                    // 4096

    const int t = threadIdx.x;
    const int base = vbid * 4096;
    cnt[t] = 0; cnt[t + 256] = 0;
    __syncthreads();

    int rs[16], rd[16], rb[16];
#pragma unroll
    for (int k = 0; k < 16; ++k) {
        int i = base + k * 256 + t;
        bool val = i < e_total;
        int s = 0, d = 0;
        if (val) {
            if (i < e_real) { s = ei[i]; d = ei[e_real + i]; }
            else            { s = d = i - e_real; }
        }
        int b = val ? (int)__umulhi((unsigned)d, M) : -1;
        rs[k] = s; rd[k] = d; rb[k] = b;
        if (val) atomicAdd(&cnt[b], 1);
    }
    __syncthreads();

    loff[t] = cnt[t]; loff[t + 256] = cnt[t + 256];
    __syncthreads();
    for (int off = 1; off < 512; off <<= 1) {
        int v0 = (t >= off) ? loff[t - off] : 0;
        int v1 = (t + 256 >= off) ? loff[t + 256 - off] : 0;
        __syncthreads();
        loff[t] += v0; loff[t + 256] += v1;
        __syncthreads();
    }
    int e0 = loff[t] - cnt[t];
    int e1 = loff[t + 256] - cnt[t + 256];
    loff[t] = e0;           loff[t + 256] = e1;
    lcur[t] = e0;           lcur[t + 256] = e1;
    gbase[t]       = t * SLAB         + atomicAdd(&bcur_pad[t * 16], cnt[t]);
    gbase[t + 256] = (t + 256) * SLAB + atomicAdd(&bcur_pad[(t + 256) * 16],
                                                  cnt[t + 256]);
    __syncthreads();

#pragma unroll
    for (int k = 0; k < 16; ++k) {
        if (rb[k] >= 0) {
            int lp = atomicAdd(&lcur[rb[k]], 1);
            ssrc[lp] = rs[k];
            sdst[lp] = rd[k];
        }
    }
    __syncthreads();

    int cn = e_total - base; if (cn > 4096) cn = 4096;
    for (int idx = t; idx < cn; idx += 256) {
        int d = sdst[idx];
        int b = (int)__umulhi((unsigned)d, M);           // recompute bucket
        int g = gbase[b] + (idx - loff[b]);
        pairs[g] = make_int2(ssrc[idx], d);              // coalesced runs
    }
}

// ------------------------- GEMM + attention logits body ---------------------
template<int K, int OUTC, int H, int C, int NPT, int KCHUNK>
__device__ __forceinline__ void gemm_al_body(char* smem, int vbid,
                                             const float* __restrict__ x,
                                             const float* __restrict__ W,
                                             const float* __restrict__ a_src,
                                             const float* __restrict__ a_dst,
                                             unsigned short* __restrict__ h,
                                             float* __restrict__ al_s,
                                             float* __restrict__ al_d,
                                             int n) {
    constexpr int COLG = OUTC / 4;
    constexpr int NG   = 256 / COLG;
    static_assert(NG * 8 == NPT, "tile mismatch");
    constexpr int LDX  = KCHUNK + 1;
    float* Xs = (float*)smem;                 // NPT*LDX
    float* Ws = Xs + NPT * LDX;               // KCHUNK*OUTC

    const int t    = threadIdx.x;
    const int mg   = t / COLG;
    const int cg   = t % COLG;
    const int base = vbid * NPT;

    float acc[8][4];
#pragma unroll
    for (int i = 0; i < 8; ++i)
#pragma unroll
        for (int j = 0; j < 4; ++j) acc[i][j] = 0.f;

    for (int kc = 0; kc < K; kc += KCHUNK) {
        __syncthreads();
        constexpr int F4R = KCHUNK / 4;
        constexpr int TOTF4 = NPT * F4R;
#pragma unroll
        for (int r = 0; r < TOTF4 / 256; ++r) {
            int f4   = r * 256 + t;
            int node = f4 / F4R;
            int kq   = f4 % F4R;
            int gn   = base + node; if (gn > n - 1) gn = n - 1;
            const float4 v = *(const float4*)&x[(size_t)gn * K + kc + kq * 4];
            float* d = &Xs[node * LDX + kq * 4];
            d[0] = v.x; d[1] = v.y; d[2] = v.z; d[3] = v.w;
        }
        constexpr int WF4 = KCHUNK * OUTC / 4;
        for (int idx = t; idx < WF4; idx += 256)
            *(float4*)&Ws[idx * 4] = *(const float4*)&W[(size_t)kc * OUTC + idx * 4];
        __syncthreads();

#pragma unroll 4
        for (int k = 0; k < KCHUNK; ++k) {
            float4 b = *(const float4*)&Ws[k * OUTC + cg * 4];
            float a[8];
#pragma unroll
            for (int i = 0; i < 8; ++i) a[i] = Xs[(mg * 8 + i) * LDX + k];
#pragma unroll
            for (int i = 0; i < 8; ++i) {
                acc[i][0] += a[i] * b.x;
                acc[i][1] += a[i] * b.y;
                acc[i][2] += a[i] * b.z;
                acc[i][3] += a[i] * b.w;
            }
        }
    }

    const float4 as4 = *(const float4*)&a_src[cg * 4];
    const float4 ad4 = *(const float4*)&a_dst[cg * 4];
    constexpr int GPH = C / 4;
    const int head = cg / GPH;
#pragma unroll
    for (int i = 0; i < 8; ++i) {
        int gn = base + mg * 8 + i;
        bool ok = gn < n;
        if (ok) {
            ushort4 hv;
            hv.x = f2bf(acc[i][0]); hv.y = f2bf(acc[i][1]);
            hv.z = f2bf(acc[i][2]); hv.w = f2bf(acc[i][3]);
            *(ushort4*)&h[(size_t)gn * OUTC + cg * 4] = hv;
        }
        float ps = acc[i][0] * as4.x + acc[i][1] * as4.y +
                   acc[i][2] * as4.z + acc[i][3] * as4.w;
        float pd = acc[i][0] * ad4.x + acc[i][1] * ad4.y +
                   acc[i][2] * ad4.z + acc[i][3] * ad4.w;
#pragma unroll
        for (int s = 1; s < GPH; s <<= 1) {
            ps += __shfl_xor(ps, s, 64);
            pd += __shfl_xor(pd, s, 64);
        }
        if (ok && (cg % GPH) == 0) {
            al_s[(size_t)gn * H + head] = ps;
            al_d[(size_t)gn * H + head] = pd;
        }
    }
}

// ------------- merged dispatch: scatter blocks + layer-1 GEMM blocks --------
__global__ __launch_bounds__(256)
void scatter_gemm_kernel(const int* __restrict__ ei, int e_real, int e_total,
                         unsigned M, int* __restrict__ bcur_pad,
                         int2* __restrict__ pairs, int ns,
                         const float* __restrict__ x,
                         const float* __restrict__ W1,
                         const float* __restrict__ as1,
                         const float* __restrict__ ad1,
                         unsigned short* __restrict__ h,
                         float* __restrict__ al_s,
                         float* __restrict__ al_d, int n) {
    __shared__ __align__(16) char smem[40960];  // max(gemm 25088, scatter 40960)
    if ((int)blockIdx.x < ns)
        scatter_body(smem, blockIdx.x, ei, e_real, e_total, M, bcur_pad, pairs);
    else
        gemm_al_body<128, 64, 8, 8, 128, 32>(smem, blockIdx.x - ns,
                                             x, W1, as1, ad1, h, al_s, al_d, n);
}

// standalone GEMM kernel (layer 2)
template<int K, int OUTC, int H, int C, int NPT, int KCHUNK>
__global__ __launch_bounds__(256)
void gemm_al_kernel(const float* __restrict__ x, const float* __restrict__ W,
                    const float* __restrict__ a_src, const float* __restrict__ a_dst,
                    unsigned short* __restrict__ h, float* __restrict__ al_s,
                    float* __restrict__ al_d, int n) {
    __shared__ __align__(16) char smem[(NPT * (KCHUNK + 1) + KCHUNK * OUTC) * 4];
    gemm_al_body<K, OUTC, H, C, NPT, KCHUNK>(smem, blockIdx.x, x, W, a_src,
                                             a_dst, h, al_s, al_d, n);
}

// one block per bucket (512): scan counts -> ebeg; LDS deg+scan -> offsets;
// LDS-cursor scatter -> srcs.
__global__ __launch_bounds__(256)
void csr_finalize_kernel(const int2* __restrict__ pairs,
                         const int* __restrict__ bcur_pad,
                         unsigned M, int n,
                         int* __restrict__ offsets,
                         int* __restrict__ srcs) {
    const int b = blockIdx.x;
    const int t = threadIdx.x;
    const unsigned long long Mll = M;
    int lo = (int)((((unsigned long long)b << 32) + Mll - 1) / Mll);
    int hi = (int)((((unsigned long long)(b + 1) << 32) + Mll - 1) / Mll);
    if (lo > n) lo = n;
    if (hi > n) hi = n;
    const int R    = hi - lo;                 // <= ~196 < 256
    const int cntb = bcur_pad[b * 16];
    const int2* sp = pairs + (size_t)b * SLAB;

    __shared__ int bs[NBUCK];
    __shared__ int ebeg_s;
    bs[t] = bcur_pad[t * 16];
    bs[t + 256] = bcur_pad[(t + 256) * 16];
    __syncthreads();
    for (int off = 1; off < NBUCK; off <<= 1) {
        int v0 = (t >= off) ? bs[t - off] : 0;
        int v1 = (t + 256 >= off) ? bs[t + 256 - off] : 0;
        __syncthreads();
        bs[t] += v0; bs[t + 256] += v1;
        __syncthreads();
    }
    if (t == 0) ebeg_s = (b == 0) ? 0 : bs[b - 1];
    if (b == NBUCK - 1 && t == 0) offsets[n] = bs[NBUCK - 1];
    __syncthreads();
    const int ebeg = ebeg_s;

    __shared__ int deg[256], sc[256], cur[256];
    deg[t] = 0;
    __syncthreads();
    for (int j = t; j < cntb; j += 256)
        atomicAdd(&deg[sp[j].y - lo], 1);
    __syncthreads();

    sc[t] = deg[t];
    __syncthreads();
    for (int off = 1; off < 256; off <<= 1) {
        int v = (t >= off) ? sc[t - off] : 0;
        __syncthreads();
        sc[t] += v;
        __syncthreads();
    }
    int e0 = sc[t] - deg[t];
    cur[t] = e0;
    if (t < R) offsets[lo + t] = ebeg + e0;
    __syncthreads();

    for (int j = t; j < cntb; j += 256) {
        int2 p = sp[j];
        int pos = atomicAdd(&cur[p.y - lo], 1);         // LDS atomic
        srcs[ebeg + pos] = p.x;
    }
}

// ------------------------- fused gather aggregation -------------------------
// wave = 1 dst node; lane = (edge_slot es, channel_group cg of 8 bf16).
// Degree-specialized wave-uniform paths; packed-fp32 accumulate.
template<int H, int C>
__global__ __launch_bounds__(256)
void gat_agg_kernel(const int* __restrict__ offsets,
                    const int* __restrict__ srcs,
                    const float* __restrict__ al_s,
                    const float* __restrict__ al_d,
                    const unsigned short* __restrict__ hfeat, // bf16
                    const float* __restrict__ bias,
                    float* __restrict__ out, int n) {
    constexpr int OUTC = H * C;
    constexpr int CG   = OUTC / 8;           // channel groups (8 or 4)
    constexpr int ES   = 64 / CG;            // edge slots (8 or 16)
    const int wid  = (int)((blockIdx.x * blockDim.x + threadIdx.x) >> 6);
    const int lane = threadIdx.x & 63;
    const int cg   = lane % CG;
    const int es   = lane / CG;
    if (wid >= n) return;
    const int head = (cg * 8) / C;

    const float aldv = al_d[(size_t)wid * H + head];
    const int beg = offsets[wid];
    const int end = offsets[wid + 1];
    const int deg = end - beg;

    v2f acc[4];
#pragma unroll
    for (int q = 0; q < 4; ++q) acc[q] = (v2f){0.f, 0.f};
    float dsum = 0.f;

    if (deg <= ES) {
        int j = beg + es;
        bool v = j < end;
        int s = __builtin_nontemporal_load(&srcs[v ? j : beg]);
        const uint4 hv = *(const uint4*)&hfeat[(size_t)s * OUTC + cg * 8];
        float ls = al_s[(size_t)s * H + head];
        float ex = v ? __expf(lrelu02(ls + aldv)) : 0.f;
        accum8(hv, ex, acc);
        dsum += ex;
    } else if (deg <= 2 * ES) {
        int sA = __builtin_nontemporal_load(&srcs[beg + es]);
        int jB = beg + ES + es;
        bool vB = jB < end;
        int sB = __builtin_nontemporal_load(&srcs[vB ? jB : beg]);
        const uint4 hvA = *(const uint4*)&hfeat[(size_t)sA * OUTC + cg * 8];
        const uint4 hvB = *(const uint4*)&hfeat[(size_t)sB * OUTC + cg * 8];
        float lsA = al_s[(size_t)sA * H + head];
        float lsB = al_s[(size_t)sB * H + head];
        float exA = __expf(lrelu02(lsA + aldv));
        float exB = vB ? __expf(lrelu02(lsB + aldv)) : 0.f;
        accum8(hvA, exA, acc);
        accum8(hvB, exB, acc);
        dsum += exA + exB;
    } else if (deg <= 4 * ES) {
        int sA = __builtin_nontemporal_load(&srcs[beg + es]);
        int sB = __builtin_nontemporal_load(&srcs[beg + ES + es]);
        int jC = beg + 2 * ES + es;
        int jD = beg + 3 * ES + es;
        bool vC = jC < end;
        bool vD = jD < end;
        int sC = __builtin_nontemporal_load(&srcs[vC ? jC : beg]);
        int sD = __builtin_nontemporal_load(&srcs[vD ? jD : beg]);
        const uint4 hvA = *(const uint4*)&hfeat[(size_t)sA * OUTC + cg * 8];
        const uint4 hvB = *(const uint4*)&hfeat[(size_t)sB * OUTC + cg * 8];
        const uint4 hvC = *(const uint4*)&hfeat[(size_t)sC * OUTC + cg * 8];
        const uint4 hvD = *(const uint4*)&hfeat[(size_t)sD * OUTC + cg * 8];
        float lsA = al_s[(size_t)sA * H + head];
        float lsB = al_s[(size_t)sB * H + head];
        float lsC = al_s[(size_t)sC * H + head];
        float lsD = al_s[(size_t)sD * H + head];
        float exA = __expf(lrelu02(lsA + aldv));
        float exB = __expf(lrelu02(lsB + aldv));
        float exC = vC ? __expf(lrelu02(lsC + aldv)) : 0.f;
        float exD = vD ? __expf(lrelu02(lsD + aldv)) : 0.f;
        accum8(hvA, exA, acc);
        accum8(hvB, exB, acc);
        accum8(hvC, exC, acc);
        accum8(hvD, exD, acc);
        dsum += (exA + exB) + (exC + exD);
    } else {
        for (int j0 = beg; j0 < end; j0 += 2 * ES) {
            int jA = j0 + es;
            int jB = j0 + ES + es;
            bool vA = jA < end;
            bool vB = jB < end;
            int sA = __builtin_nontemporal_load(&srcs[vA ? jA : beg]);
            int sB = __builtin_nontemporal_load(&srcs[vB ? jB : beg]);
            const uint4 hvA = *(const uint4*)&hfeat[(size_t)sA * OUTC + cg * 8];
            const uint4 hvB = *(const uint4*)&hfeat[(size_t)sB * OUTC + cg * 8];
            float lsA = al_s[(size_t)sA * H + head];
            float lsB = al_s[(size_t)sB * H + head];
            float exA = vA ? __expf(lrelu02(lsA + aldv)) : 0.f;
            float exB = vB ? __expf(lrelu02(lsB + aldv)) : 0.f;
            accum8(hvA, exA, acc);
            accum8(hvB, exB, acc);
            dsum += exA + exB;
        }
    }

#pragma unroll
    for (int sh = CG; sh < 64; sh <<= 1) {
        dsum += __shfl_xor(dsum, sh, 64);
#pragma unroll
        for (int q = 0; q < 4; ++q) acc[q] += shfl_xor_v2(acc[q], sh);
    }

    if (es == 0) {
        float inv = 1.f / dsum;
        const float4 b0 = *(const float4*)&bias[cg * 8];
        const float4 b1v = *(const float4*)&bias[cg * 8 + 4];
        float4 o0, o1;
        o0.x = acc[0].x * inv + b0.x;
        o0.y = acc[0].y * inv + b0.y;
        o0.z = acc[1].x * inv + b0.z;
        o0.w = acc[1].y * inv + b0.w;
        o1.x = acc[2].x * inv + b1v.x;
        o1.y = acc[2].y * inv + b1v.y;
        o1.z = acc[3].x * inv + b1v.z;
        o1.w = acc[3].y * inv + b1v.w;
        *(float4*)&out[(size_t)wid * OUTC + cg * 8]     = o0;
        *(float4*)&out[(size_t)wid * OUTC + cg * 8 + 4] = o1;
    }
}

// ---------------------------------------------------------------------------

extern "C" void kernel_launch(void* const* d_in, const int* in_sizes, int n_in,
                              void* d_out, int out_size, void* d_ws, size_t ws_size,
                              hipStream_t stream) {
    const float* x   = (const float*)d_in[0];
    const int*   ei  = (const int*)  d_in[1];
    const float* W1  = (const float*)d_in[2];
    const float* as1 = (const float*)d_in[3];
    const float* ad1 = (const float*)d_in[4];
    const float* b1  = (const float*)d_in[5];
    const float* W2  = (const float*)d_in[6];
    const float* as2 = (const float*)d_in[7];
    const float* ad2 = (const float*)d_in[8];
    const float* b2  = (const float*)d_in[9];
    float* out = (float*)d_out;

    const int n       = in_sizes[0] / 128;   // 100000
    const int e_real  = in_sizes[1] / 2;     // 1600000
    const int e_total = e_real + n;
    const unsigned M512 = (unsigned)(((unsigned long long)NBUCK << 32) / (unsigned)n);

    // ------------- workspace layout -------------
    unsigned short* h1u = (unsigned short*)d_ws;       // n*64 bf16 (l2: n*32)
    float* fws  = (float*)d_ws;
    float* als1 = fws  + (size_t)n * 32;               // n*8  (l2: n)
    float* ald1 = als1 + (size_t)n * 8;                // n*8  (l2: n)
    float* agg1 = ald1 + (size_t)n * 8;                // n*64 fp32 (layer1 out)
    int2*  pairs = (int2*)agg1;                        // ALIAS: NBUCK*SLAB int2
    int* offsets  = (int*)(agg1 + (size_t)n * 64);     // n+1
    int* srcs     = offsets + (n + 1);                 // e_total
    int* bcur_pad = srcs + e_total;                    // NBUCK*16

    const int ns = (e_total + 4095) / 4096;            // scatter blocks (416)
    const int g1 = (n + 127) / 128;                    // gemm1 blocks (782)

    // ------------- CSR build + layer-1 GEMM (merged) -------------
    hipMemsetAsync(bcur_pad, 0, NBUCK * 16 * sizeof(int), stream);
    scatter_gemm_kernel<<<ns + g1, 256, 0, stream>>>(
        ei, e_real, e_total, M512, bcur_pad, pairs, ns,
        x, W1, as1, ad1, h1u, als1, ald1, n);
    csr_finalize_kernel<<<NBUCK, 256, 0, stream>>>(pairs, bcur_pad, M512, n,
                                                   offsets, srcs);

    // ------------- layer 1 aggregation -------------
    gat_agg_kernel<8, 8><<<(n + 3) / 4, 256, 0, stream>>>(
        offsets, srcs, als1, ald1, h1u, b1, agg1, n);

    // ------------- layer 2: K=64, H=1, C=32 -------------
    gemm_al_kernel<64, 32, 1, 32, 256, 32><<<(n + 255) / 256, 256, 0, stream>>>(
        agg1, W2, as2, ad2, h1u, als1, ald1, n);
    gat_agg_kernel<1, 32><<<(n + 3) / 4, 256, 0, stream>>>(
        offsets, srcs, als1, ald1, h1u, b2, out, n);
}